// Round 7
// baseline (217.534 us; speedup 1.0000x reference)
//
#include <hip/hip_runtime.h>
#include <hip/hip_cooperative_groups.h>
#include <math.h>

namespace cg = cooperative_groups;

#define MB_    32
#define ATOM_  64
#define HID_   64
#define NRBF_  300
#define GAMMA_ 10.0f
#define RES_   0.1f

// filter table: f2(d) sampled at TPTS points, step TSTEP, domain [0, 10]
#define TPTS      2001
#define TSTEP     0.005f
#define INV_TSTEP 200.0f

// truncated RBF window: terms with |d - 0.1 r| > ~1.4 contribute < 5e-9
#define RWIN 28

// workspace layout (float offsets)
#define T_OFF   0
#define T_SZ    (TPTS * 64)          // 128064
#define V1_OFF  (T_OFF + T_SZ)       // 128064
#define V1_SZ   (MB_ * 64 * 64)      // 131072
#define W2T_OFF (V1_OFF + V1_SZ)     // 259136
#define W3T_OFF (W2T_OFF + 4096)     // 263232
// total 267328 floats = 1,069,312 bytes of d_ws

__device__ __forceinline__ float sp_f(float x) {
    return fmaxf(x, 0.f) + log1pf(__expf(-fabsf(x)));
}

// ---------------------------------------------------------------------------
// One cooperative kernel, 512 blocks x 256 threads (2 blocks/CU co-resident).
// Phase A (block b):
//   - v1 slice: m = b>>4, rows 4*(b&15)..+3 of v1[m] = x[m] @ W1^T + b1
//   - table samples s = 4b..4b+3 (one per wave), truncated-RBF filter MLP
//   - b < 16: transpose W2, W3 into ws
// grid.sync()
// Phase B (block b): m = b>>4, j = 4*(b&15) + wave; full per-wave CFConv
//   aggregation via table lerp + W2/W3 tail + residual.   (R6 main body)
// ---------------------------------------------------------------------------
__global__ __launch_bounds__(256, 2)
void schnet_one(const float* __restrict__ x,   const float* __restrict__ dist,
                const float* __restrict__ W1,  const float* __restrict__ b1,
                const float* __restrict__ W2,  const float* __restrict__ b2,
                const float* __restrict__ W3,  const float* __restrict__ b3,
                const float* __restrict__ Wd1, const float* __restrict__ bd1,
                const float* __restrict__ Wd2, const float* __restrict__ bd2,
                float* __restrict__ ws,        float* __restrict__ out)
{
    __shared__ float sw1 [64 * 65];  // W1 [o][c], pad 65 (2-way banks max)
    __shared__ float sxr [4 * 64];   // 4 rows of x[m]
    __shared__ float su  [4 * 64];   // per-wave u vectors (table path)
    __shared__ float sDist[64 * 4];  // phase B: [i][jj]
    __shared__ float sAgg [4 * 64];
    __shared__ float sV   [4 * 64];

    const int b   = blockIdx.x;
    const int tid = threadIdx.x;
    const int c   = tid & 63;        // lane / channel
    const int p   = tid >> 6;        // wave id

    const int m  = b >> 4;
    const int q  = b & 15;

    // ================= Phase A =================
    // ---- stage W1 and this block's 4 x-rows ----
    for (int e = tid; e < 4096; e += 256) {
        int o = e >> 6, cc = e & 63;
        sw1[o * 65 + cc] = W1[e];
    }
    {
        int row = tid >> 6, col = tid & 63;
        sxr[row * 64 + col] = x[m * 4096 + (4 * q + row) * 64 + col];
    }
    __syncthreads();

    // ---- v1 slice: thread (i=p, o=c) ----
    {
        float a0 = b1[c], a1 = 0.f;
        #pragma unroll
        for (int k = 0; k < 64; k += 2) {
            a0 = fmaf(sxr[p * 64 + k],     sw1[c * 65 + k],     a0);  // sxr: broadcast
            a1 = fmaf(sxr[p * 64 + k + 1], sw1[c * 65 + k + 1], a1);  // sw1: 2-way
        }
        ws[V1_OFF + (m * 64 + 4 * q + p) * 64 + c] = a0 + a1;
    }

    // ---- table: one d-sample per wave, truncated RBF in registers ----
    {
        const int s  = 4 * b + p;
        const int se = min(s, TPTS - 1);
        const float d = se * TSTEP;

        int r0 = (int)ceilf((d - 1.35f) * 10.0f);
        r0 = max(r0, 0);                          // r0 + RWIN - 1 <= 114 < 300

        float a0 = bd1[c], a1 = 0.f;
        const float* wrow1 = Wd1 + c * NRBF_ + r0;
        #pragma unroll
        for (int k = 0; k < RWIN; k += 2) {
            float t0 = fmaf(-RES_, (float)(r0 + k),     d);
            float t1 = fmaf(-RES_, (float)(r0 + k + 1), d);
            float w0 = __expf(-GAMMA_ * t0 * t0);
            float w1 = __expf(-GAMMA_ * t1 * t1);
            a0 = fmaf(w0, wrow1[k],     a0);
            a1 = fmaf(w1, wrow1[k + 1], a1);
        }
        su[p * 64 + c] = sp_f(a0 + a1);
        __syncthreads();

        const float4* wrow2 = (const float4*)(Wd2 + c * 64);
        const float*  uu    = su + p * 64;
        float s0 = bd2[c], s1 = 0.f, s2 = 0.f, s3 = 0.f;
        #pragma unroll
        for (int h4 = 0; h4 < 16; ++h4) {
            float4 wv = wrow2[h4];
            s0 = fmaf(wv.x, uu[4 * h4 + 0], s0);   // uu: broadcast
            s1 = fmaf(wv.y, uu[4 * h4 + 1], s1);
            s2 = fmaf(wv.z, uu[4 * h4 + 2], s2);
            s3 = fmaf(wv.w, uu[4 * h4 + 3], s3);
        }
        if (s < TPTS)
            ws[T_OFF + s * 64 + c] = sp_f((s0 + s1) + (s2 + s3));
    }

    // ---- W2^T / W3^T (blocks 0..15) ----
    if (b < 16) {
        int e = b * 256 + tid;       // 16 * 256 = 4096
        int o = e >> 6, cc = e & 63;
        ws[W2T_OFF + cc * 64 + o] = W2[e];
        ws[W3T_OFF + cc * 64 + o] = W3[e];
    }

    __threadfence();                 // ws writes device-visible
    cg::this_grid().sync();

    // ================= Phase B =================  (R6 main body)
    const int j0 = q * 4;

    if (tid < 64) {
        float4 dv = *(const float4*)(dist + (m * ATOM_ + tid) * ATOM_ + j0);
        *(float4*)(sDist + tid * 4) = dv;
    }
    __syncthreads();

    const float* Tb  = ws + T_OFF;
    const float* v1m = ws + V1_OFF + m * 4096;
    float acc = 0.f;
    #pragma unroll 8
    for (int ii = 0; ii < 64; ++ii) {
        float d  = sDist[ii * 4 + p];               // wave-uniform broadcast
        float f  = d * INV_TSTEP;
        int   s  = min((int)f, TPTS - 2);
        float fr = f - (float)s;
        const float* Tr = Tb + s * 64;
        float t0 = Tr[c], t1 = Tr[64 + c];          // coalesced 256B rows
        float f2v = fmaf(fr, t1 - t0, t0);
        acc = fmaf(f2v, v1m[ii * 64 + c], acc);     // shared across 4 waves -> L1
    }
    sAgg[p * 64 + c] = acc;
    __syncthreads();

    {
        const float* W2t = ws + W2T_OFF;
        const float* ag  = sAgg + p * 64;
        float s0 = b2[c], s1 = 0.f;
        #pragma unroll 16
        for (int cc = 0; cc < 64; cc += 2) {
            s0 = fmaf(ag[cc],     W2t[cc * 64 + c],       s0);
            s1 = fmaf(ag[cc + 1], W2t[(cc + 1) * 64 + c], s1);
        }
        sV[p * 64 + c] = sp_f(s0 + s1);
    }
    __syncthreads();

    {
        const float* W3t = ws + W3T_OFF;
        const float* vv  = sV + p * 64;
        float s0 = b3[c], s1 = 0.f;
        #pragma unroll 16
        for (int oo = 0; oo < 64; oo += 2) {
            s0 = fmaf(vv[oo],     W3t[oo * 64 + c],       s0);
            s1 = fmaf(vv[oo + 1], W3t[(oo + 1) * 64 + c], s1);
        }
        const int idx = (m * ATOM_ + j0 + p) * HID_ + c;
        out[idx] = (s0 + s1) + x[idx];
    }
}

extern "C" void kernel_launch(void* const* d_in, const int* in_sizes, int n_in,
                              void* d_out, int out_size, void* d_ws, size_t ws_size,
                              hipStream_t stream) {
    const float* x   = (const float*)d_in[0];
    const float* dist= (const float*)d_in[1];
    const float* W1  = (const float*)d_in[2];
    const float* b1  = (const float*)d_in[3];
    const float* W2  = (const float*)d_in[4];
    const float* b2  = (const float*)d_in[5];
    const float* W3  = (const float*)d_in[6];
    const float* b3  = (const float*)d_in[7];
    const float* Wd1 = (const float*)d_in[8];
    const float* bd1 = (const float*)d_in[9];
    const float* Wd2 = (const float*)d_in[10];
    const float* bd2 = (const float*)d_in[11];
    float* out = (float*)d_out;
    float* ws  = (float*)d_ws;
    (void)in_sizes; (void)n_in; (void)out_size; (void)ws_size;
    // needs ~1.07 MB of d_ws (table + v1 + W2^T/W3^T)

    void* args[] = { (void*)&x, (void*)&dist, (void*)&W1, (void*)&b1,
                     (void*)&W2, (void*)&b2,  (void*)&W3, (void*)&b3,
                     (void*)&Wd1,(void*)&bd1, (void*)&Wd2,(void*)&bd2,
                     (void*)&ws, (void*)&out };
    hipLaunchCooperativeKernel((const void*)schnet_one, dim3(512), dim3(256),
                               args, 0, stream);
}

// Round 8
// 94.008 us; speedup vs baseline: 2.3140x; 2.3140x over previous
//
#include <hip/hip_runtime.h>
#include <math.h>

#define MB_    32
#define ATOM_  64
#define HID_   64
#define NRBF_  300
#define GAMMA_ 10.0f
#define RES_   0.1f

// filter table: f2(d) sampled at TPTS points, step TSTEP, domain [0, 10]
#define TPTS      2001
#define TSTEP     0.005f
#define INV_TSTEP 200.0f

// truncated RBF window: terms with |d - 0.1 r| > ~1.4 contribute < 5e-9
#define RWIN 28

// workspace layout (float offsets)
#define T_OFF   0
#define T_SZ    (TPTS * 64)          // 128064
#define V1_OFF  (T_OFF + T_SZ)       // 128064
#define V1_SZ   (MB_ * 64 * 64)      // 131072
#define W2T_OFF (V1_OFF + V1_SZ)     // 259136
#define W3T_OFF (W2T_OFF + 4096)     // 263232
// total 267328 floats = 1,069,312 bytes of d_ws

__device__ __forceinline__ float sp_f(float x) {
    return fmaxf(x, 0.f) + log1pf(__expf(-fabsf(x)));
}

// ---------------------------------------------------------------------------
// prep: blocks [0,32)   -> v1[m] = x[m] @ W1^T + b1   (4x4 register tile)
//       blocks [32,533) -> filter table rows, truncated-RBF, barrier-light
//       block  533      -> W2^T, W3^T for coalesced tail reads
// ---------------------------------------------------------------------------
__global__ __launch_bounds__(256)
void schnet_prep(const float* __restrict__ x,   const float* __restrict__ W1,
                 const float* __restrict__ b1,  const float* __restrict__ W2,
                 const float* __restrict__ W3,  const float* __restrict__ Wd1,
                 const float* __restrict__ bd1, const float* __restrict__ Wd2,
                 const float* __restrict__ bd2, float* __restrict__ ws)
{
    __shared__ float smem[8320];     // 33.3 KB, unioned between branches
    const int tid = threadIdx.x;
    const int b   = blockIdx.x;

    if (b < MB_) {
        // ---- v1 = x[m] @ W1^T + b1, 4x4 register tile per thread ----
        float* sx = smem;            // x[m]  [64][65] (pad -> <=2-way banks)
        float* sw = smem + 4160;     // W1    [64][65]
        const float* xm = x + b * 4096;
        for (int e = tid; e < 4096; e += 256) {
            int i = e >> 6, c = e & 63;
            sx[i * 65 + c] = xm[e];
            sw[i * 65 + c] = W1[e];
        }
        __syncthreads();
        const int tx = tid & 15;         // o-tile: o = 4*tx + bb
        const int ty = tid >> 4;         // i-tile: i = 4*ty + aa
        float acc[4][4];
        #pragma unroll
        for (int aa = 0; aa < 4; ++aa)
            #pragma unroll
            for (int bb = 0; bb < 4; ++bb)
                acc[aa][bb] = b1[4 * tx + bb];
        #pragma unroll 8
        for (int k = 0; k < 64; ++k) {
            float xa[4], wb[4];
            #pragma unroll
            for (int aa = 0; aa < 4; ++aa) xa[aa] = sx[(4 * ty + aa) * 65 + k];  // broadcast
            #pragma unroll
            for (int bb = 0; bb < 4; ++bb) wb[bb] = sw[(4 * tx + bb) * 65 + k];  // 2-way
            #pragma unroll
            for (int aa = 0; aa < 4; ++aa)
                #pragma unroll
                for (int bb = 0; bb < 4; ++bb)
                    acc[aa][bb] = fmaf(xa[aa], wb[bb], acc[aa][bb]);
        }
        #pragma unroll
        for (int aa = 0; aa < 4; ++aa) {
            float4 v = make_float4(acc[aa][0], acc[aa][1], acc[aa][2], acc[aa][3]);
            *(float4*)(ws + V1_OFF + (b * 64 + 4 * ty + aa) * 64 + 4 * tx) = v;
        }
    } else if (b < MB_ + 501) {
        // ---- table: one d-sample per wave, truncated RBF in registers ----
        float* su = smem;                // [4][64] per-wave u vectors
        const int sub = tid >> 6, c = tid & 63;
        const int s  = (b - MB_) * 4 + sub;
        const int se = min(s, TPTS - 1);         // dead waves compute, don't store
        const float d = se * TSTEP;

        int r0 = (int)ceilf((d - 1.35f) * 10.0f);
        r0 = max(r0, 0);                          // r0+RWIN-1 <= 114 < 300 always

        float a0 = bd1[c], a1 = 0.f;
        const float* wrow1 = Wd1 + c * NRBF_ + r0;
        #pragma unroll
        for (int k = 0; k < RWIN; k += 2) {
            float t0 = fmaf(-RES_, (float)(r0 + k),     d);
            float t1 = fmaf(-RES_, (float)(r0 + k + 1), d);
            float w0 = __expf(-GAMMA_ * t0 * t0);
            float w1 = __expf(-GAMMA_ * t1 * t1);
            a0 = fmaf(w0, wrow1[k],     a0);
            a1 = fmaf(w1, wrow1[k + 1], a1);
        }
        su[sub * 64 + c] = sp_f(a0 + a1);
        __syncthreads();

        // f2[o] = sp( sum_h Wd2[o][h] * u[h] + bd2[o] ), o = lane
        const float4* wrow2 = (const float4*)(Wd2 + c * 64);
        const float*  uu    = su + sub * 64;
        float s0 = bd2[c], s1 = 0.f, s2 = 0.f, s3 = 0.f;
        #pragma unroll
        for (int h4 = 0; h4 < 16; ++h4) {
            float4 wv = wrow2[h4];
            s0 = fmaf(wv.x, uu[4 * h4 + 0], s0);   // uu reads: all-lane broadcast
            s1 = fmaf(wv.y, uu[4 * h4 + 1], s1);
            s2 = fmaf(wv.z, uu[4 * h4 + 2], s2);
            s3 = fmaf(wv.w, uu[4 * h4 + 3], s3);
        }
        if (s < TPTS)
            ws[T_OFF + s * 64 + c] = sp_f((s0 + s1) + (s2 + s3));
    } else {
        // ---- transpose W2, W3 ----
        for (int e = tid; e < 4096; e += 256) {
            int o = e >> 6, c = e & 63;
            ws[W2T_OFF + c * 64 + o] = W2[e];
            ws[W3T_OFF + c * 64 + o] = W3[e];
        }
    }
}

// ---------------------------------------------------------------------------
// main: one block per (m, j).  agg[c] = sum_i v1[m,i,c] * lerp(T, d_ij)[c]
//       then v2 = sp(agg @ W2^T + b2); out = x + v2 @ W3^T + b3
// ---------------------------------------------------------------------------
__global__ __launch_bounds__(256)
void schnet_main(const float* __restrict__ x, const float* __restrict__ dist,
                 const float* __restrict__ b2, const float* __restrict__ b3,
                 const float* __restrict__ ws, float* __restrict__ out)
{
    __shared__ float sD[64];
    __shared__ float sRed[4 * 64];
    const int m   = blockIdx.x >> 6;
    const int j   = blockIdx.x & 63;
    const int tid = threadIdx.x;
    const int c   = tid & 63;        // channel this thread owns (lane)
    const int p   = tid >> 6;        // wave = i-quarter

    if (tid < 64) sD[tid] = dist[(m * ATOM_ + tid) * ATOM_ + j];
    __syncthreads();

    const float* Tb  = ws + T_OFF;
    const float* v1m = ws + V1_OFF + (m * 64 + p * 16) * 64;
    float acc = 0.f;
    #pragma unroll
    for (int ii = 0; ii < 16; ++ii) {
        float d  = sD[p * 16 + ii];                 // LDS broadcast
        float f  = d * INV_TSTEP;
        int   s  = min((int)f, TPTS - 2);
        float fr = f - (float)s;
        const float* Tr = Tb + s * 64;
        float t0 = Tr[c], t1 = Tr[64 + c];          // coalesced 256B rows
        float f2v = fmaf(fr, t1 - t0, t0);
        acc = fmaf(f2v, v1m[ii * 64 + c], acc);     // coalesced, L1/L2-hit
    }
    sRed[p * 64 + c] = acc;
    __syncthreads();
    if (tid < 64)
        sD[tid] = sRed[tid] + sRed[64 + tid] + sRed[128 + tid] + sRed[192 + tid];
    __syncthreads();

    // v2_pre = agg @ W2^T : thread (o=c, quarter=p) does 16 MACs, coalesced W2T
    {
        const float* W2t = ws + W2T_OFF;
        float s_ = 0.f;
        #pragma unroll
        for (int cc = 0; cc < 16; ++cc)
            s_ = fmaf(sD[16 * p + cc], W2t[(16 * p + cc) * 64 + c], s_);
        sRed[p * 64 + c] = s_;
    }
    __syncthreads();
    if (tid < 64)
        sD[tid] = sp_f(sRed[tid] + sRed[64 + tid] + sRed[128 + tid] + sRed[192 + tid] + b2[tid]);
    __syncthreads();
    {
        const float* W3t = ws + W3T_OFF;
        float s_ = 0.f;
        #pragma unroll
        for (int cc = 0; cc < 16; ++cc)
            s_ = fmaf(sD[16 * p + cc], W3t[(16 * p + cc) * 64 + c], s_);
        sRed[p * 64 + c] = s_;
    }
    __syncthreads();
    if (tid < 64) {
        float v_ = sRed[tid] + sRed[64 + tid] + sRed[128 + tid] + sRed[192 + tid] + b3[tid];
        out[(m * ATOM_ + j) * HID_ + tid] = v_ + x[(m * ATOM_ + j) * HID_ + tid];
    }
}

extern "C" void kernel_launch(void* const* d_in, const int* in_sizes, int n_in,
                              void* d_out, int out_size, void* d_ws, size_t ws_size,
                              hipStream_t stream) {
    const float* x   = (const float*)d_in[0];
    const float* dist= (const float*)d_in[1];
    const float* W1  = (const float*)d_in[2];
    const float* b1  = (const float*)d_in[3];
    const float* W2  = (const float*)d_in[4];
    const float* b2  = (const float*)d_in[5];
    const float* W3  = (const float*)d_in[6];
    const float* b3  = (const float*)d_in[7];
    const float* Wd1 = (const float*)d_in[8];
    const float* bd1 = (const float*)d_in[9];
    const float* Wd2 = (const float*)d_in[10];
    const float* bd2 = (const float*)d_in[11];
    float* out = (float*)d_out;
    float* ws  = (float*)d_ws;
    (void)in_sizes; (void)n_in; (void)out_size; (void)ws_size;
    // needs ~1.07 MB of d_ws (table + v1 + W2^T/W3^T)

    schnet_prep<<<dim3(MB_ + 501 + 1), dim3(256), 0, stream>>>(
        x, W1, b1, W2, W3, Wd1, bd1, Wd2, bd2, ws);
    schnet_main<<<dim3(MB_ * ATOM_), dim3(256), 0, stream>>>(
        x, dist, b2, b3, ws, out);
}